// Round 10
// baseline (6272.430 us; speedup 1.0000x reference)
//
#include <hip/hip_runtime.h>
#include <hip/hip_bf16.h>

// LSTM: L=1024, B=64, I=512, H=512, fp32 in/out.
// Persistent kernel, 256 WGs x 256 thr (1 WG/CU). 8 clusters x 32 WGs;
// cluster = 8 batches; wave = 16 gate rows (4 h-idx x 4 gates). Weights in
// VGPRs as MFMA B-fragments; C state in registers.
// SPECULATIVE h-load (round 9) + CORRECT init pattern (round 10):
//   code = h_bits ^ (((t>>1)&1)?0xFFFF:0).  |h|<=1.0 => bf16 exp<=127 =>
//   bit14==0; coded parity-1 form has bit14==1. Validator tests bit14 ONLY.
//   Consumer loads h speculatively, validates bit14 pattern, falls back to
//   the flag-wait + paced retries on miss.
// ROUND-9 BUG: hx memset byte 0xBF -> u16 0xBFBF has bit14=0 => VALIDATES
//   as parity-0 data; early speculative reads consumed init garbage.
// FIX: memset byte 0x7F -> u16 0x7F7F, bit14=1 => fails parity-0 check.
//   Init data is only ever seen by parity-0 readers (t=1 reads t=0's writes,
//   t=2 reads t=1's writes; both pmask=0): t>=3 readers touch slots whose
//   every location was validated-as-overwritten two steps earlier. Stale
//   real data across steps is caught by parity alternation; cross-replay
//   staleness is erased by this launch-time memset.
// Slot-overwrite safety: producer reaches step t's stores only after
// validating ALL of step t-1, which requires every wave's t-1 stores,
// which (program order) requires those waves finished reading t-2 — so the
// slot being overwritten (t&1 == (t-2)&1) is never still-needed.

typedef __attribute__((ext_vector_type(8))) short bf16x8;
typedef __attribute__((ext_vector_type(4))) float f32x4;

#define NT 1024
#define NB 64
#define NH 512
#define NI 512

#define FLAGS_OFF 0        // u32[8][128]  (4 KiB)
#define HX_OFF    4096     // u16[2][64][512] (128 KiB)
#define HX_BYTES  (2 * NB * NH * 2)

#define VBITS 0x4000400040004000ULL   // bit14 of each u16 lane

__device__ __forceinline__ bf16x8 pack8(float4 a, float4 b) {
    union U2 { __hip_bfloat162 h; unsigned int u; } c0, c1, c2, c3;
    c0.h = __float22bfloat162_rn(make_float2(a.x, a.y));
    c1.h = __float22bfloat162_rn(make_float2(a.z, a.w));
    c2.h = __float22bfloat162_rn(make_float2(b.x, b.y));
    c3.h = __float22bfloat162_rn(make_float2(b.z, b.w));
    union R { bf16x8 v; unsigned int u[4]; } r;
    r.u[0] = c0.u; r.u[1] = c1.u; r.u[2] = c2.u; r.u[3] = c3.u;
    return r.v;
}

__device__ __forceinline__ float sigm(float v) {
    return 1.0f / (1.0f + __expf(-v));
}
__device__ __forceinline__ float tanh_f(float v) {
    float e = __expf(-2.0f * fabsf(v));        // in (0,1], no overflow
    float r = (1.0f - e) / (1.0f + e);         // <= 1 in fp32
    return copysignf(r, v);
}

__global__ __launch_bounds__(256, 1) void lstm_fused(
    const float* __restrict__ x,
    const float* __restrict__ h0,
    const float* __restrict__ c0,
    const float* __restrict__ Wf, const float* __restrict__ Bf,
    const float* __restrict__ Wi, const float* __restrict__ Bi,
    const float* __restrict__ Wc, const float* __restrict__ Bc,
    const float* __restrict__ Wo, const float* __restrict__ Bo,
    float* __restrict__ out,
    unsigned char* __restrict__ ws)
{
    unsigned int*   flags = (unsigned int*)(ws + FLAGS_OFF);
    unsigned short* hx    = (unsigned short*)(ws + HX_OFF);

    const int tid  = threadIdx.x;
    const int wv   = tid >> 6;            // wave 0..3
    const int lane = tid & 63;
    const int n    = lane & 15;           // D col (gate row within wave tile)
    const int kg   = lane >> 4;           // k-group 0..3
    const int cl   = blockIdx.x & 7;      // cluster (XCD-swizzle heuristic)
    const int wg   = blockIdx.x >> 3;     // WG within cluster, 0..31

    const int jj = (wv << 2) + (n >> 2);          // 0..15 within WG
    const int j  = (wg << 4) + jj;                // global h index
    const int g  = n & 3;                         // 0=f 1=i 2=c 3=o

    const float* Wg = (g == 0) ? Wf : (g == 1) ? Wi : (g == 2) ? Wc : Wo;
    const float* Bg = (g == 0) ? Bf : (g == 1) ? Bi : (g == 2) ? Bc : Bo;

    const int m_a   = (n < 8) ? n : 7;            // A-row batch (8..15 dup)
    const int bglob = cl * 8 + m_a;

    // ---- prologue: static B-fragments (weights, bf16) into VGPRs ----
    bf16x8 bfrag[32];
    {
        const float* wrow = Wg + (size_t)j * (NH + NI);
        #pragma unroll
        for (int kb = 0; kb < 32; ++kb) {
            const float* p = wrow + kb * 32 + kg * 8;
            bfrag[kb] = pack8(*(const float4*)(p), *(const float4*)(p + 4));
        }
    }
    const float bias_v = Bg[j];

    const bool active = (g == 0) && (kg < 2);     // 8 lanes/wave x 4 regs
    float Cst[4];
    #pragma unroll
    for (int r = 0; r < 4; ++r)
        Cst[r] = active ? c0[(size_t)(cl * 8 + kg * 4 + r) * NH + j] : 0.0f;

    unsigned int* fb = flags + cl * 128;          // 128 wave-flags, 512 B
    const int myflag = wg * 4 + wv;

    for (int t = 0; t < NT; ++t) {
        // -- x fragments + x-partial MFMAs (independent of other waves) --
        const float* xrow = x + ((size_t)t * NB + bglob) * NI;
        bf16x8 xfrag[16];
        #pragma unroll
        for (int q = 0; q < 16; ++q) {
            const float* p = xrow + q * 32 + kg * 8;
            xfrag[q] = pack8(*(const float4*)(p), *(const float4*)(p + 4));
        }
        f32x4 a0 = {bias_v, bias_v, bias_v, bias_v};
        f32x4 a1 = {0.f, 0.f, 0.f, 0.f};
        f32x4 a2 = {0.f, 0.f, 0.f, 0.f};
        f32x4 a3 = {0.f, 0.f, 0.f, 0.f};
        #pragma unroll
        for (int q = 0; q < 16; q += 4) {
            a0 = __builtin_amdgcn_mfma_f32_16x16x32_bf16(xfrag[q],     bfrag[16 + q],     a0, 0, 0, 0);
            a1 = __builtin_amdgcn_mfma_f32_16x16x32_bf16(xfrag[q + 1], bfrag[16 + q + 1], a1, 0, 0, 0);
            a2 = __builtin_amdgcn_mfma_f32_16x16x32_bf16(xfrag[q + 2], bfrag[16 + q + 2], a2, 0, 0, 0);
            a3 = __builtin_amdgcn_mfma_f32_16x16x32_bf16(xfrag[q + 3], bfrag[16 + q + 3], a3, 0, 0, 0);
        }

        // -- h fragments: SPECULATIVE load + parity validate; flag fallback --
        bf16x8 hfrag[16];
        if (t == 0) {
            const float* hrow = h0 + (size_t)bglob * NH;
            #pragma unroll
            for (int q = 0; q < 16; ++q) {
                const float* p = hrow + q * 32 + kg * 8;
                hfrag[q] = pack8(*(const float4*)(p), *(const float4*)(p + 4));
            }
        } else {
            const unsigned long long pm64 =
                (((t - 1) >> 1) & 1) ? ~0ULL : 0ULL;
            const unsigned short* hrow =
                hx + ((size_t)((t - 1) & 1) * NB + bglob) * NH;
            int attempt = 0;
            for (;;) {
                unsigned long long accb = 0;
                #pragma unroll
                for (int q = 0; q < 16; ++q) {
                    const unsigned long long* p =
                        (const unsigned long long*)(hrow + q * 32 + kg * 8);
                    union { bf16x8 v; unsigned long long u[2]; } un;
                    unsigned long long w0 = __hip_atomic_load(
                        p, __ATOMIC_RELAXED, __HIP_MEMORY_SCOPE_AGENT) ^ pm64;
                    unsigned long long w1 = __hip_atomic_load(
                        p + 1, __ATOMIC_RELAXED, __HIP_MEMORY_SCOPE_AGENT) ^ pm64;
                    accb |= w0;
                    accb |= w1;
                    un.u[0] = w0;
                    un.u[1] = w1;
                    hfrag[q] = un.v;
                }
                if (__all((accb & VBITS) == 0ULL)) break;   // all fresh
                ++attempt;
                if (attempt == 1) {
                    // fallback gate: wait for all 128 producer flags once
                    const unsigned int tgt = (unsigned int)t;
                    const unsigned long long* fp =
                        (const unsigned long long*)fb + lane;
                    int guard = 1 << 20;
                    for (;;) {
                        unsigned long long fv = __hip_atomic_load(
                            fp, __ATOMIC_RELAXED, __HIP_MEMORY_SCOPE_AGENT);
                        bool ok = ((unsigned int)fv >= tgt) &&
                                  ((unsigned int)(fv >> 32) >= tgt);
                        if (__all(ok)) break;
                        if (--guard == 0) break;
                        __builtin_amdgcn_s_sleep(1);
                    }
                } else {
                    __builtin_amdgcn_s_sleep(2);            // paced retry
                }
                if (attempt > (1 << 12)) break;             // hang safety
            }
            __builtin_amdgcn_sched_barrier(0);
        }

        #pragma unroll
        for (int q = 0; q < 16; q += 4) {
            a0 = __builtin_amdgcn_mfma_f32_16x16x32_bf16(hfrag[q],     bfrag[q],     a0, 0, 0, 0);
            a1 = __builtin_amdgcn_mfma_f32_16x16x32_bf16(hfrag[q + 1], bfrag[q + 1], a1, 0, 0, 0);
            a2 = __builtin_amdgcn_mfma_f32_16x16x32_bf16(hfrag[q + 2], bfrag[q + 2], a2, 0, 0, 0);
            a3 = __builtin_amdgcn_mfma_f32_16x16x32_bf16(hfrag[q + 3], bfrag[q + 3], a3, 0, 0, 0);
        }
        f32x4 acc = (a0 + a1) + (a2 + a3);

        // -- gather f/i/c/o in 4-lane groups, elementwise, coded h-store --
        unsigned short* hxout = hx + (size_t)(t & 1) * NB * NH;
        const unsigned int pmask = ((t >> 1) & 1) ? 0xFFFFu : 0u;
        float harr[4];
        #pragma unroll
        for (int r = 0; r < 4; ++r) {
            float fv = acc[r];
            float iv = __shfl_xor(fv, 1);
            float gv = __shfl_xor(fv, 2);
            float ov = __shfl_xor(fv, 3);
            if (active) {
                float ft = sigm(fv);
                float it = sigm(iv);
                float gt = tanh_f(gv);
                float ot = sigm(ov);
                float Cn = ft * Cst[r] + it * gt;
                Cst[r] = Cn;
                float ht = ot * tanh_f(Cn);       // |ht| <= 1.0 in fp32
                harr[r] = ht;
                int m = kg * 4 + r;               // batch within cluster
                __hip_bfloat16 hb = __float2bfloat16(ht);
                unsigned short code =
                    (unsigned short)((*(unsigned short*)&hb) ^ pmask);
                __hip_atomic_store(
                    (unsigned short*)(hxout + (size_t)(cl * 8 + m) * NH + j),
                    code, __ATOMIC_RELAXED, __HIP_MEMORY_SCOPE_AGENT);
            }
        }

        // -- advisory flag: NO drain (parity is the real gate) --
        __builtin_amdgcn_sched_barrier(0);        // keep flag after h-stores
        if (lane == 0)
            __hip_atomic_store(fb + myflag, (unsigned int)(t + 1),
                               __ATOMIC_RELAXED, __HIP_MEMORY_SCOPE_AGENT);

        // -- fp32 output stores AFTER publish (off the critical path) --
        if (active) {
            #pragma unroll
            for (int r = 0; r < 4; ++r) {
                int m = kg * 4 + r;
                out[((size_t)t * NB + cl * 8 + m) * NH + j] = harr[r];
            }
        }
    }
}

extern "C" void kernel_launch(void* const* d_in, const int* in_sizes, int n_in,
                              void* d_out, int out_size, void* d_ws, size_t ws_size,
                              hipStream_t stream) {
    const float* x  = (const float*)d_in[0];
    const float* h0 = (const float*)d_in[1];
    const float* c0 = (const float*)d_in[2];
    const float* Wf = (const float*)d_in[3];
    const float* Bf = (const float*)d_in[4];
    const float* Wi = (const float*)d_in[5];
    const float* Bi = (const float*)d_in[6];
    const float* Wc = (const float*)d_in[7];
    const float* Bc = (const float*)d_in[8];
    const float* Wo = (const float*)d_in[9];
    const float* Bo = (const float*)d_in[10];
    float* out = (float*)d_out;

    // Flags: zero each launch (monotonic, must restart).
    hipMemsetAsync(d_ws, 0, 4096, stream);
    // hx: 0x7F each launch -> u16 0x7F7F has bit14 == 1, so it FAILS the
    // parity-0 validator (bit14==0 expected). Init data is only ever
    // reachable by parity-0 readers (t=1, t=2) — see header proof.
    hipMemsetAsync((char*)d_ws + HX_OFF, 0x7F, HX_BYTES, stream);

    lstm_fused<<<dim3(256), dim3(256), 0, stream>>>(
        x, h0, c0, Wf, Bf, Wi, Bi, Wc, Bc, Wo, Bo, out,
        (unsigned char*)d_ws);
}